// Round 7
// baseline (445.205 us; speedup 1.0000x reference)
//
#include <hip/hip_runtime.h>

// ---------------------------------------------------------------------------
// TextGCN (2-layer GCN, eval mode) on MI355X.
// Fusions:
//   * xw1_word = word @ (W_lin@W1) + (b_lin@W1)  (never materialize [N,768] x)
//   * layer 2: agg(h1@W2)[mask] == agg(h1)[mask] @ W2
// CSR holds RAW weights at build; after degdis a sequential prenorm pass folds
// dis[src] into entries.y, so agg kernels do zero dis gathers. Self-loop gets
// reserved slot offs[i] (no atomic). xw1/h1 stored bf16 (halves gather bytes).
// Dense projections: bf16 MFMA 16x16x32, wave-per-16-rows, no LDS/barriers,
// A-row register prefetch (2-deep) hides HBM latency. Edge passes process 4
// edges/thread for 4-way atomic-chain ILP.
// ---------------------------------------------------------------------------

typedef __attribute__((ext_vector_type(8))) short short8;   // 8 bf16 = 4 VGPR
typedef __attribute__((ext_vector_type(4))) float float4v;  // MFMA C/D frag

__device__ __forceinline__ unsigned short f2bf(float f) {   // RNE f32->bf16
  unsigned u = __float_as_uint(f);
  return (unsigned short)((u + 0x7FFFu + ((u >> 16) & 1u)) >> 16);
}
__device__ __forceinline__ float bf2f(unsigned short u) {
  return __uint_as_float((unsigned)u << 16);
}

// pack W[K,64] fp32 -> bf16 fragment order: pack[((g*nk0+k0)*64+lane)*8+j]
// holds W[k0*32+quad*8+j][(lane&15)+16g], zero-padded past K.
__device__ __forceinline__ void pack_w_body(const float* __restrict__ W, int K,
                                            int nk0, unsigned short* __restrict__ pack,
                                            int tid) {
  int lane = tid & 63;
  int rest = tid >> 6;
  int k0 = rest % nk0;
  int g = rest / nk0;
  int quad = lane >> 4;
  int n = (lane & 15) + g * 16;
  short8 v;
#pragma unroll
  for (int j = 0; j < 8; ++j) {
    int k = k0 * 32 + quad * 8 + j;
    float w = (k < K) ? W[(size_t)k * 64 + n] : 0.f;
    v[j] = (short)f2bf(w);
  }
  *(short8*)(pack + (((size_t)(g * nk0 + k0) * 64 + lane) << 3)) = v;
}

// MFMA GEMM: out[R,64] = X[R,K(ldx)] @ W[K,64] (+bias). One wave = 16 rows.
// A-row loads prefetched one k0 ahead (registers only, no LDS/barriers).
template <bool LAST, bool PACKED, bool BF16OUT>
__device__ __forceinline__ void mfma_gemm_body(
    const float* __restrict__ X, int ldx, const float* __restrict__ lastRow,
    const unsigned short* __restrict__ Wpack, const float* __restrict__ Wf,
    int nk0, int K, const float* __restrict__ bias,
    void* __restrict__ outv, int R, int waveIdx) {
  int r0 = waveIdx * 16;
  if (r0 >= R) return;
  const int lane = threadIdx.x & 63;
  const int quad = lane >> 4;
  const int m = lane & 15;
  const int row = r0 + m;
  const float* xrow = nullptr;
  if (row < R) xrow = (LAST && row == R - 1) ? lastRow : X + (size_t)row * ldx;

  float4v acc[4];
#pragma unroll
  for (int g = 0; g < 4; ++g) acc[g] = (float4v){0.f, 0.f, 0.f, 0.f};

  auto loadA = [&](int k0, float* a) {
    int kb = k0 * 32 + quad * 8;
    if (xrow && kb + 8 <= K) {
      float4 v0 = *(const float4*)(xrow + kb);
      float4 v1 = *(const float4*)(xrow + kb + 4);
      a[0] = v0.x; a[1] = v0.y; a[2] = v0.z; a[3] = v0.w;
      a[4] = v1.x; a[5] = v1.y; a[6] = v1.z; a[7] = v1.w;
    } else {
#pragma unroll
      for (int j = 0; j < 8; ++j) {
        int k = kb + j;
        a[j] = (xrow && k < K) ? xrow[k] : 0.f;
      }
    }
  };
  auto compute = [&](const float* a, int k0) {
    short8 af;
#pragma unroll
    for (int j = 0; j < 8; ++j) af[j] = (short)f2bf(a[j]);
#pragma unroll
    for (int g = 0; g < 4; ++g) {
      short8 bf;
      if (PACKED) {
        bf = *(const short8*)(Wpack + (((size_t)(g * nk0 + k0) * 64 + lane) << 3));
      } else {
        int kb = k0 * 32 + quad * 8;
        int n = g * 16 + m;
#pragma unroll
        for (int j = 0; j < 8; ++j) {
          int k = kb + j;
          float w = (k < K) ? Wf[(size_t)k * 64 + n] : 0.f;
          bf[j] = (short)f2bf(w);
        }
      }
      acc[g] = __builtin_amdgcn_mfma_f32_16x16x32_bf16(af, bf, acc[g], 0, 0, 0);
    }
  };

  float aA[8], aB[8];
  loadA(0, aA);
  for (int k0 = 0; k0 < nk0; k0 += 2) {
    if (k0 + 1 < nk0) loadA(k0 + 1, aB);
    compute(aA, k0);
    if (k0 + 1 >= nk0) break;
    if (k0 + 2 < nk0) loadA(k0 + 2, aA);
    compute(aB, k0 + 1);
  }

#pragma unroll
  for (int g = 0; g < 4; ++g) {
    float b = bias ? bias[g * 16 + m] : 0.f;
#pragma unroll
    for (int reg = 0; reg < 4; ++reg) {
      int r = r0 + quad * 4 + reg;    // C/D: col=lane&15, row=quad*4+reg
      if (r < R) {
        float o = acc[g][reg] + b;
        if (BF16OUT) ((unsigned short*)outv)[(size_t)r * 64 + g * 16 + m] = f2bf(o);
        else ((float*)outv)[(size_t)r * 64 + g * 16 + m] = o;
      }
    }
  }
}

// phase1: [fuseBlocks) fuse GEMM [Wlin;blin]@W1 -> WfuseB (strided fp32 B);
//         [+packBlocks) pack W1; rest: cnt histogram, 4 edges/thread.
__global__ __launch_bounds__(256) void k_phase1(
    const float* __restrict__ Wlin, const float* __restrict__ blin,
    const float* __restrict__ W1, float* __restrict__ WfuseB,
    unsigned short* __restrict__ packW1,
    const int* __restrict__ ei, int E, int* __restrict__ cnt,
    int fuseBlocks, int packBlocks) {
  int b = blockIdx.x;
  if (b < fuseBlocks) {
    mfma_gemm_body<true, false, false>(Wlin, 768, blin, nullptr, W1, 24, 768,
                                       nullptr, WfuseB, 301, b * 4 + (threadIdx.x >> 6));
    return;
  }
  b -= fuseBlocks;
  if (b < packBlocks) {
    pack_w_body(W1, 768, 24, packW1, b * 256 + threadIdx.x);
    return;
  }
  b -= packBlocks;
  int e0 = (b * 256 + threadIdx.x) * 4;
#pragma unroll
  for (int j = 0; j < 4; ++j) {
    int e = e0 + j;
    if (e < E) atomicAdd(cnt + ei[E + e], 1);   // fire-and-forget
  }
}

// ---- scan of (cnt[i]+1) -> offs[N+1]; also packs Wfuse & W2 in reduce pass ----
__global__ void k_scan_reduce(const int* __restrict__ cnt, int N, int* __restrict__ bsum,
                              const float* __restrict__ WfuseB, unsigned short* __restrict__ packWf,
                              const float* __restrict__ W2, unsigned short* __restrict__ packW2,
                              int nb) {
  int b = blockIdx.x, t = threadIdx.x;
  if (b >= nb) {
    b -= nb;
    if (b < 10) pack_w_body(WfuseB, 300, 10, packWf, b * 256 + t);
    else pack_w_body(W2, 64, 2, packW2, (b - 10) * 256 + t);
    return;
  }
  __shared__ int sd[256];
  int base = b * 1024 + t * 4;
  int s = 0;
#pragma unroll
  for (int j = 0; j < 4; ++j) s += (base + j < N) ? cnt[base + j] + 1 : 0;
  sd[t] = s; __syncthreads();
  for (int off = 128; off > 0; off >>= 1) {
    if (t < off) sd[t] += sd[t + off];
    __syncthreads();
  }
  if (t == 0) bsum[b] = sd[0];
}

__global__ void k_scan_small(int* __restrict__ bsum, int nb) {
  __shared__ int s[128];
  int t = threadIdx.x;
  int v = (t < nb) ? bsum[t] : 0;
  s[t] = v; __syncthreads();
  for (int off = 1; off < 128; off <<= 1) {
    int x = (t >= off) ? s[t - off] : 0;
    __syncthreads();
    s[t] += x;
    __syncthreads();
  }
  if (t < nb) bsum[t] = s[t] - v;   // exclusive
}

__global__ void k_scan_final(const int* __restrict__ cnt, int N, const int* __restrict__ bsum,
                             int* __restrict__ offs, int* __restrict__ cursor,
                             int2* __restrict__ entries) {
  __shared__ int sd[256];
  int b = blockIdx.x, t = threadIdx.x;
  int base = b * 1024 + t * 4;
  int v[4], loc = 0;
#pragma unroll
  for (int j = 0; j < 4; ++j) { v[j] = (base + j < N) ? cnt[base + j] + 1 : 0; loc += v[j]; }
  sd[t] = loc; __syncthreads();
  for (int off = 1; off < 256; off <<= 1) {
    int x = (t >= off) ? sd[t - off] : 0;
    __syncthreads();
    sd[t] += x;
    __syncthreads();
  }
  int run = bsum[b] + sd[t] - loc;
#pragma unroll
  for (int j = 0; j < 4; ++j) {
    if (base + j < N) {
      int i = base + j;
      offs[i] = run;
      cursor[i] = run + 1;                               // slot 0 = self loop
      entries[run] = make_int2(i, __float_as_int(1.0f)); // raw w=1
      run += v[j];
    }
  }
  if (b == gridDim.x - 1 && t == 255) offs[N] = run;  // total = N + E
}

// phase2: [fillBlocks) CSR fill (4 edges/thread); [+docBlocks) doc MFMA; rest word.
__global__ __launch_bounds__(256) void k_phase2(
    const int* __restrict__ ei, const float* __restrict__ ew, int E,
    int* __restrict__ cursor, int2* __restrict__ entries,
    const float* __restrict__ doc, const unsigned short* __restrict__ packW1,
    unsigned short* __restrict__ xw1, int ND,
    const float* __restrict__ wordf, const unsigned short* __restrict__ packWf,
    const float* __restrict__ bfuse, unsigned short* __restrict__ xw1word, int NW,
    int fillBlocks, int docBlocks) {
  int b = blockIdx.x;
  if (b < fillBlocks) {
    int e0 = (b * 256 + threadIdx.x) * 4;
    int src[4], dst[4];
    float w[4];
#pragma unroll
    for (int j = 0; j < 4; ++j) {
      int e = e0 + j;
      if (e < E) { src[j] = ei[e]; dst[j] = ei[E + e]; w[j] = ew[e]; }
    }
    int pos[4];
#pragma unroll
    for (int j = 0; j < 4; ++j)
      if (e0 + j < E) pos[j] = atomicAdd(cursor + dst[j], 1);   // 4 independent chains
#pragma unroll
    for (int j = 0; j < 4; ++j)
      if (e0 + j < E) entries[pos[j]] = make_int2(src[j], __float_as_int(w[j]));
    return;
  }
  b -= fillBlocks;
  if (b < docBlocks) {
    mfma_gemm_body<false, true, true>(doc, 768, nullptr, packW1, nullptr, 24, 768,
                                      nullptr, xw1, ND, b * 4 + (threadIdx.x >> 6));
  } else {
    b -= docBlocks;
    mfma_gemm_body<false, true, true>(wordf, 300, nullptr, packWf, nullptr, 10, 300,
                                      bfuse, xw1word, NW, b * 4 + (threadIdx.x >> 6));
  }
}

// deg->dis: segmented sum of RAW weights over CSR rows (atomic-free)
__global__ void k_degdis(const int2* __restrict__ entries, const int* __restrict__ offs,
                         float* __restrict__ dis, int N) {
  int i = blockIdx.x * blockDim.x + threadIdx.x;
  if (i >= N) return;
  int p = offs[i], pe = offs[i + 1];
  float d = 0.f;
  for (; p < pe; ++p) d += __int_as_float(entries[p].y);
  dis[i] = d > 0.f ? rsqrtf(fmaxf(d, 1e-12f)) : 0.f;
}

// fold dis[src] into entries.y (sequential read/modify/write, coalesced)
__global__ void k_prenorm(int2* __restrict__ entries, const float* __restrict__ dis, int NE) {
  int p = blockIdx.x * blockDim.x + threadIdx.x;
  if (p >= NE) return;
  int2 e = entries[p];
  entries[p].y = __float_as_int(__int_as_float(e.y) * dis[e.x]);
}

// gather-accumulate over one CSR row (prenormed weights, bf16 x), 8-wide
__device__ __forceinline__ float row_gather(const unsigned short* __restrict__ xin,
                                            const int2* __restrict__ entries,
                                            int p, int pe, int lane) {
  float acc = 0.f;
  for (; p < pe; p += 8) {
    int idx[8]; float w[8];
#pragma unroll
    for (int j = 0; j < 8; ++j) {
      int q = p + j;
      bool valid = q < pe;
      int2 e = entries[valid ? q : pe - 1];   // row always has >=1 entry (self loop)
      idx[j] = e.x;
      w[j] = valid ? __int_as_float(e.y) : 0.f;
    }
    float x[8];
#pragma unroll
    for (int j = 0; j < 8; ++j) x[j] = bf2f(xin[(size_t)idx[j] * 64 + lane]);
#pragma unroll
    for (int j = 0; j < 8; ++j) acc = fmaf(x[j], w[j], acc);
  }
  return acc;
}

// layer-1 aggregation: h1[i] = relu(b1 + dis[i]*sum wn*x[src]) (bf16 out)
__global__ void k_agg(const unsigned short* __restrict__ xin, const int2* __restrict__ entries,
                      const int* __restrict__ offs, const float* __restrict__ dis,
                      const float* __restrict__ bias, unsigned short* __restrict__ xout, int N) {
  const int lane = threadIdx.x & 63;
  const int wv = threadIdx.x >> 6;
  int i = blockIdx.x * 4 + wv;
  if (i >= N) return;
  float acc = row_gather(xin, entries, offs[i], offs[i + 1], lane);
  acc = fmaf(acc, dis[i], bias[lane]);
  acc = fmaxf(acc, 0.f);
  xout[(size_t)i * 64 + lane] = f2bf(acc);
}

// masked layer-2 aggregation (no bias/relu; final GEMM adds b2) + emit y[mask]
__global__ void k_agg2m(const unsigned short* __restrict__ xin, const int2* __restrict__ entries,
                        const int* __restrict__ offs, const float* __restrict__ dis,
                        const int* __restrict__ mask, const int* __restrict__ y,
                        float* __restrict__ tout, float* __restrict__ outY, int M) {
  const int lane = threadIdx.x & 63;
  const int wv = threadIdx.x >> 6;
  int o = blockIdx.x * 4 + wv;
  if (o >= M) return;
  int i = mask[o];
  float acc = row_gather(xin, entries, offs[i], offs[i + 1], lane);
  tout[(size_t)o * 64 + lane] = acc * dis[i];
  if (lane == 0) outY[o] = (float)y[i];
}

// final projection [M,64]@[64,64]+b2 via MFMA (packed W2), fp32 out
__global__ __launch_bounds__(256) void k_mfma_final(
    const float* __restrict__ X, const unsigned short* __restrict__ packW2,
    const float* __restrict__ b2, float* __restrict__ out, int M) {
  mfma_gemm_body<false, true, false>(X, 64, nullptr, packW2, nullptr, 2, 64,
                                     b2, out, M, blockIdx.x * 4 + (threadIdx.x >> 6));
}

extern "C" void kernel_launch(void* const* d_in, const int* in_sizes, int n_in,
                              void* d_out, int out_size, void* d_ws, size_t ws_size,
                              hipStream_t stream) {
  const float* doc   = (const float*)d_in[0];
  const float* wordf = (const float*)d_in[1];
  const float* ew    = (const float*)d_in[2];
  const float* Wlin  = (const float*)d_in[3];
  const float* blin  = (const float*)d_in[4];
  const float* W1    = (const float*)d_in[5];
  const float* b1    = (const float*)d_in[6];
  const float* W2    = (const float*)d_in[7];
  const float* b2    = (const float*)d_in[8];
  const int*   ei    = (const int*)d_in[9];
  const int*   mask  = (const int*)d_in[10];
  const int*   y     = (const int*)d_in[11];

  const int E  = in_sizes[2];
  const int M  = in_sizes[10];
  const int ND = in_sizes[0] / 768;
  const int NW = in_sizes[1] / 300;
  const int N  = ND + NW;
  const int NE = N + E;

  // workspace carve (aligned 256B)
  char* p = (char*)d_ws;
  auto carve = [&](size_t bytes) -> void* {
    void* q = (void*)p;
    p += (bytes + 255) & ~(size_t)255;
    return q;
  };
  float*          WfuseB = (float*)carve(301 * 64 * 4);
  unsigned short* packW1 = (unsigned short*)carve((size_t)4 * 24 * 64 * 8 * 2);
  unsigned short* packWf = (unsigned short*)carve((size_t)4 * 10 * 64 * 8 * 2);
  unsigned short* packW2 = (unsigned short*)carve((size_t)4 * 2 * 64 * 8 * 2);
  float* dis    = (float*)carve((size_t)N * 4);
  int*   cnt    = (int*)carve((size_t)N * 4);
  int*   offs   = (int*)carve(((size_t)N + 1) * 4);
  int*   cursor = (int*)carve((size_t)N * 4);
  int*   bsum   = (int*)carve(1024);
  int2*  entries = (int2*)carve((size_t)NE * 8);
  unsigned short* xw1 = (unsigned short*)carve((size_t)N * 64 * 2);  // bf16
  unsigned short* h1  = (unsigned short*)carve((size_t)N * 64 * 2);  // bf16
  float* tmask = (float*)carve((size_t)M * 64 * 4);

  hipMemsetAsync(cnt, 0, (size_t)N * 4, stream);

  // phase1: fuse MFMA (strided B) || pack W1 || cnt histogram (4 edges/thr)
  const int fuseBlocks = (301 + 63) / 64;
  const int packBlocks = 24;
  const int cntBlocks  = (E + 1023) / 1024;
  k_phase1<<<fuseBlocks + packBlocks + cntBlocks, 256, 0, stream>>>(
      Wlin, blin, W1, WfuseB, packW1, ei, E, cnt, fuseBlocks, packBlocks);

  int nb = (N + 1023) / 1024;
  k_scan_reduce<<<nb + 12, 256, 0, stream>>>(cnt, N, bsum, WfuseB, packWf, W2, packW2, nb);
  k_scan_small<<<1, 128, 0, stream>>>(bsum, nb);
  k_scan_final<<<nb, 256, 0, stream>>>(cnt, N, bsum, offs, cursor, entries);

  // phase2: CSR fill (4 edges/thr) || doc MFMA || word MFMA
  const int fillBlocks = (E + 1023) / 1024;
  const int docBlocks  = (ND + 63) / 64;
  const int wordBlocks = (NW + 63) / 64;
  k_phase2<<<fillBlocks + docBlocks + wordBlocks, 256, 0, stream>>>(
      ei, ew, E, cursor, entries,
      doc, packW1, xw1, ND,
      wordf, packWf, WfuseB + (size_t)300 * 64, xw1 + (size_t)ND * 64, NW,
      fillBlocks, docBlocks);

  k_degdis<<<(N + 255) / 256, 256, 0, stream>>>(entries, offs, dis, N);
  k_prenorm<<<(NE + 255) / 256, 256, 0, stream>>>(entries, dis, NE);

  // layer-1 aggregation (+b1, relu) -> bf16 h1
  k_agg<<<(N + 3) / 4, 256, 0, stream>>>(xw1, entries, offs, dis, b1, h1, N);

  // layer-2: masked aggregation over h1, then project [M,64]@[64,64]+b2
  float* out0 = (float*)d_out;
  float* outY = out0 + (size_t)M * 64;
  k_agg2m<<<(M + 3) / 4, 256, 0, stream>>>(h1, entries, offs, dis, mask, y, tmask, outY, M);
  k_mfma_final<<<(M + 63) / 64, 256, 0, stream>>>(tmask, packW2, b2, out0, M);
}

// Round 8
// 420.424 us; speedup vs baseline: 1.0589x; 1.0589x over previous
//
#include <hip/hip_runtime.h>

// ---------------------------------------------------------------------------
// TextGCN (2-layer GCN, eval mode) on MI355X.
// Fusions:
//   * xw1_word = word @ (W_lin@W1) + (b_lin@W1)  (never materialize [N,768] x)
//   * layer 2: agg(h1@W2)[mask] == agg(h1)[mask] @ W2
// CSR holds RAW weights at build; degdis computes dis; prenorm folds dis[src]
// into entries.y. Self-loop has reserved slot offs[i] (no atomic).
// xw1/h1 stored bf16 in PERMUTED column order pi(pos)=(pos&3)*16+(pos>>2) so
// MFMA epilogue stores are 4x coalesced 8B instead of 16x scattered 2B.
// Gather kernels are layout-agnostic; b1 indexed via pi; packW2 k-rows
// permuted via pi so the final MFMA consumes permuted tmask directly.
// Dispatches: phase1(fuse||packW1||cnt) -> scans -> k_fill -> k_gemms(degdis
// || docMFMA || wordMFMA) -> prenorm -> agg -> agg2m -> final.
// ---------------------------------------------------------------------------

typedef __attribute__((ext_vector_type(8))) short short8;   // 8 bf16 = 4 VGPR
typedef __attribute__((ext_vector_type(4))) float float4v;  // MFMA C/D frag

__device__ __forceinline__ unsigned short f2bf(float f) {   // RNE f32->bf16
  unsigned u = __float_as_uint(f);
  return (unsigned short)((u + 0x7FFFu + ((u >> 16) & 1u)) >> 16);
}
__device__ __forceinline__ float bf2f(unsigned short u) {
  return __uint_as_float((unsigned)u << 16);
}
__device__ __forceinline__ int permcol(int p) {   // pi: pos -> true col
  return ((p & 3) << 4) | (p >> 2);
}

// pack W[K,64] fp32 -> bf16 fragment order: pack[((g*nk0+k0)*64+lane)*8+j]
// holds W[ksrc][(lane&15)+16g], ksrc = PERM ? pi(k) : k; zero past K.
template <bool PERM>
__device__ __forceinline__ void pack_w_body(const float* __restrict__ W, int K,
                                            int nk0, unsigned short* __restrict__ pack,
                                            int tid) {
  int lane = tid & 63;
  int rest = tid >> 6;
  int k0 = rest % nk0;
  int g = rest / nk0;
  int quad = lane >> 4;
  int n = (lane & 15) + g * 16;
  short8 v;
#pragma unroll
  for (int j = 0; j < 8; ++j) {
    int k = k0 * 32 + quad * 8 + j;
    int ks = PERM ? permcol(k) : k;
    float w = (k < K) ? W[(size_t)ks * 64 + n] : 0.f;
    v[j] = (short)f2bf(w);
  }
  *(short8*)(pack + (((size_t)(g * nk0 + k0) * 64 + lane) << 3)) = v;
}

// MFMA GEMM: out[R,64] = X[R,K(ldx)] @ W[K,64] (+bias). One wave = 16 rows.
// A-row register prefetch (2-deep). BF16PERM: packed permuted bf16 stores.
template <bool LAST, bool PACKED, bool BF16PERM>
__device__ __forceinline__ void mfma_gemm_body(
    const float* __restrict__ X, int ldx, const float* __restrict__ lastRow,
    const unsigned short* __restrict__ Wpack, const float* __restrict__ Wf,
    int nk0, int K, const float* __restrict__ bias,
    void* __restrict__ outv, int R, int waveIdx) {
  int r0 = waveIdx * 16;
  if (r0 >= R) return;
  const int lane = threadIdx.x & 63;
  const int quad = lane >> 4;
  const int m = lane & 15;
  const int row = r0 + m;
  const float* xrow = nullptr;
  if (row < R) xrow = (LAST && row == R - 1) ? lastRow : X + (size_t)row * ldx;

  float4v acc[4];
#pragma unroll
  for (int g = 0; g < 4; ++g) acc[g] = (float4v){0.f, 0.f, 0.f, 0.f};

  auto loadA = [&](int k0, float* a) {
    int kb = k0 * 32 + quad * 8;
    if (xrow && kb + 8 <= K) {
      float4 v0 = *(const float4*)(xrow + kb);
      float4 v1 = *(const float4*)(xrow + kb + 4);
      a[0] = v0.x; a[1] = v0.y; a[2] = v0.z; a[3] = v0.w;
      a[4] = v1.x; a[5] = v1.y; a[6] = v1.z; a[7] = v1.w;
    } else {
#pragma unroll
      for (int j = 0; j < 8; ++j) {
        int k = kb + j;
        a[j] = (xrow && k < K) ? xrow[k] : 0.f;
      }
    }
  };
  auto compute = [&](const float* a, int k0) {
    short8 af;
#pragma unroll
    for (int j = 0; j < 8; ++j) af[j] = (short)f2bf(a[j]);
#pragma unroll
    for (int g = 0; g < 4; ++g) {
      short8 bf;
      if (PACKED) {
        bf = *(const short8*)(Wpack + (((size_t)(g * nk0 + k0) * 64 + lane) << 3));
      } else {
        int kb = k0 * 32 + quad * 8;
        int n = g * 16 + m;
#pragma unroll
        for (int j = 0; j < 8; ++j) {
          int k = kb + j;
          float w = (k < K) ? Wf[(size_t)k * 64 + n] : 0.f;
          bf[j] = (short)f2bf(w);
        }
      }
      acc[g] = __builtin_amdgcn_mfma_f32_16x16x32_bf16(af, bf, acc[g], 0, 0, 0);
    }
  };

  float aA[8], aB[8];
  loadA(0, aA);
  for (int k0 = 0; k0 < nk0; k0 += 2) {
    if (k0 + 1 < nk0) loadA(k0 + 1, aB);
    compute(aA, k0);
    if (k0 + 1 >= nk0) break;
    if (k0 + 2 < nk0) loadA(k0 + 2, aA);
    compute(aB, k0 + 1);
  }

  if (BF16PERM) {
    // lane m packs cols {m,16+m,32+m,48+m} of row r0+quad*4+j as 4 bf16 (8B)
    float b0 = bias ? bias[m] : 0.f;
    float b1 = bias ? bias[16 + m] : 0.f;
    float b2 = bias ? bias[32 + m] : 0.f;
    float b3 = bias ? bias[48 + m] : 0.f;
#pragma unroll
    for (int j = 0; j < 4; ++j) {
      int r = r0 + quad * 4 + j;
      if (r < R) {
        ushort4 pk;
        pk.x = f2bf(acc[0][j] + b0);
        pk.y = f2bf(acc[1][j] + b1);
        pk.z = f2bf(acc[2][j] + b2);
        pk.w = f2bf(acc[3][j] + b3);
        *(ushort4*)((unsigned short*)outv + ((size_t)r * 64 + m * 4)) = pk;
      }
    }
  } else {
#pragma unroll
    for (int g = 0; g < 4; ++g) {
      float b = bias ? bias[g * 16 + m] : 0.f;
#pragma unroll
      for (int reg = 0; reg < 4; ++reg) {
        int r = r0 + quad * 4 + reg;    // C/D: col=lane&15, row=quad*4+reg
        if (r < R) ((float*)outv)[(size_t)r * 64 + g * 16 + m] = acc[g][reg] + b;
      }
    }
  }
}

// phase1: [fuseBlocks) fuse GEMM [Wlin;blin]@W1 -> WfuseB (strided fp32 B);
//         [+packBlocks) pack W1; rest: cnt histogram, 4 edges/thread.
__global__ __launch_bounds__(256) void k_phase1(
    const float* __restrict__ Wlin, const float* __restrict__ blin,
    const float* __restrict__ W1, float* __restrict__ WfuseB,
    unsigned short* __restrict__ packW1,
    const int* __restrict__ ei, int E, int* __restrict__ cnt,
    int fuseBlocks, int packBlocks) {
  int b = blockIdx.x;
  if (b < fuseBlocks) {
    mfma_gemm_body<true, false, false>(Wlin, 768, blin, nullptr, W1, 24, 768,
                                       nullptr, WfuseB, 301, b * 4 + (threadIdx.x >> 6));
    return;
  }
  b -= fuseBlocks;
  if (b < packBlocks) {
    pack_w_body<false>(W1, 768, 24, packW1, b * 256 + threadIdx.x);
    return;
  }
  b -= packBlocks;
  int e0 = (b * 256 + threadIdx.x) * 4;
#pragma unroll
  for (int j = 0; j < 4; ++j) {
    int e = e0 + j;
    if (e < E) atomicAdd(cnt + ei[E + e], 1);   // fire-and-forget
  }
}

// ---- scan of (cnt[i]+1) -> offs[N+1]; also packs Wfuse & W2(permuted) ----
__global__ void k_scan_reduce(const int* __restrict__ cnt, int N, int* __restrict__ bsum,
                              const float* __restrict__ WfuseB, unsigned short* __restrict__ packWf,
                              const float* __restrict__ W2, unsigned short* __restrict__ packW2,
                              int nb) {
  int b = blockIdx.x, t = threadIdx.x;
  if (b >= nb) {
    b -= nb;
    if (b < 10) pack_w_body<false>(WfuseB, 300, 10, packWf, b * 256 + t);
    else pack_w_body<true>(W2, 64, 2, packW2, (b - 10) * 256 + t);
    return;
  }
  __shared__ int sd[256];
  int base = b * 1024 + t * 4;
  int s = 0;
#pragma unroll
  for (int j = 0; j < 4; ++j) s += (base + j < N) ? cnt[base + j] + 1 : 0;
  sd[t] = s; __syncthreads();
  for (int off = 128; off > 0; off >>= 1) {
    if (t < off) sd[t] += sd[t + off];
    __syncthreads();
  }
  if (t == 0) bsum[b] = sd[0];
}

__global__ void k_scan_small(int* __restrict__ bsum, int nb) {
  __shared__ int s[128];
  int t = threadIdx.x;
  int v = (t < nb) ? bsum[t] : 0;
  s[t] = v; __syncthreads();
  for (int off = 1; off < 128; off <<= 1) {
    int x = (t >= off) ? s[t - off] : 0;
    __syncthreads();
    s[t] += x;
    __syncthreads();
  }
  if (t < nb) bsum[t] = s[t] - v;   // exclusive
}

__global__ void k_scan_final(const int* __restrict__ cnt, int N, const int* __restrict__ bsum,
                             int* __restrict__ offs, int* __restrict__ cursor,
                             int2* __restrict__ entries) {
  __shared__ int sd[256];
  int b = blockIdx.x, t = threadIdx.x;
  int base = b * 1024 + t * 4;
  int v[4], loc = 0;
#pragma unroll
  for (int j = 0; j < 4; ++j) { v[j] = (base + j < N) ? cnt[base + j] + 1 : 0; loc += v[j]; }
  sd[t] = loc; __syncthreads();
  for (int off = 1; off < 256; off <<= 1) {
    int x = (t >= off) ? sd[t - off] : 0;
    __syncthreads();
    sd[t] += x;
    __syncthreads();
  }
  int run = bsum[b] + sd[t] - loc;
#pragma unroll
  for (int j = 0; j < 4; ++j) {
    if (base + j < N) {
      int i = base + j;
      offs[i] = run;
      cursor[i] = run + 1;                               // slot 0 = self loop
      entries[run] = make_int2(i, __float_as_int(1.0f)); // raw w=1
      run += v[j];
    }
  }
  if (b == gridDim.x - 1 && t == 255) offs[N] = run;  // total = N + E
}

// CSR fill only (4 edges/thread, 4 independent atomic chains)
__global__ __launch_bounds__(256) void k_fill(
    const int* __restrict__ ei, const float* __restrict__ ew, int E,
    int* __restrict__ cursor, int2* __restrict__ entries) {
  int e0 = (blockIdx.x * 256 + threadIdx.x) * 4;
  int src[4], dst[4];
  float w[4];
#pragma unroll
  for (int j = 0; j < 4; ++j) {
    int e = e0 + j;
    if (e < E) { src[j] = ei[e]; dst[j] = ei[E + e]; w[j] = ew[e]; }
  }
  int pos[4];
#pragma unroll
  for (int j = 0; j < 4; ++j)
    if (e0 + j < E) pos[j] = atomicAdd(cursor + dst[j], 1);
#pragma unroll
  for (int j = 0; j < 4; ++j)
    if (e0 + j < E) entries[pos[j]] = make_int2(src[j], __float_as_int(w[j]));
}

// k_gemms: [degBlocks) deg->dis (atomic-free); [+docBlocks) doc MFMA; rest word.
__global__ __launch_bounds__(256) void k_gemms(
    const int2* __restrict__ entries, const int* __restrict__ offs,
    float* __restrict__ dis, int N, int degBlocks,
    const float* __restrict__ doc, const unsigned short* __restrict__ packW1,
    unsigned short* __restrict__ xw1, int ND, int docBlocks,
    const float* __restrict__ wordf, const unsigned short* __restrict__ packWf,
    const float* __restrict__ bfuse, unsigned short* __restrict__ xw1word, int NW) {
  int b = blockIdx.x;
  if (b < degBlocks) {
    int i = b * 256 + threadIdx.x;
    if (i >= N) return;
    int p = offs[i], pe = offs[i + 1];
    float d = 0.f;
    for (; p < pe; ++p) d += __int_as_float(entries[p].y);
    dis[i] = d > 0.f ? rsqrtf(fmaxf(d, 1e-12f)) : 0.f;
    return;
  }
  b -= degBlocks;
  if (b < docBlocks) {
    mfma_gemm_body<false, true, true>(doc, 768, nullptr, packW1, nullptr, 24, 768,
                                      nullptr, xw1, ND, b * 4 + (threadIdx.x >> 6));
  } else {
    b -= docBlocks;
    mfma_gemm_body<false, true, true>(wordf, 300, nullptr, packWf, nullptr, 10, 300,
                                      bfuse, xw1word, NW, b * 4 + (threadIdx.x >> 6));
  }
}

// fold dis[src] into entries.y (sequential r/m/w, coalesced)
__global__ void k_prenorm(int2* __restrict__ entries, const float* __restrict__ dis, int NE) {
  int p = blockIdx.x * blockDim.x + threadIdx.x;
  if (p >= NE) return;
  int2 e = entries[p];
  entries[p].y = __float_as_int(__int_as_float(e.y) * dis[e.x]);
}

// gather-accumulate over one CSR row (prenormed weights, bf16 x), 8/4/2/1 tail
__device__ __forceinline__ float row_gather(const unsigned short* __restrict__ xin,
                                            const int2* __restrict__ entries,
                                            int p, int pe, int lane) {
  float acc = 0.f;
  for (; p + 8 <= pe; p += 8) {
    int2 e[8];
#pragma unroll
    for (int j = 0; j < 8; ++j) e[j] = entries[p + j];
    float x[8];
#pragma unroll
    for (int j = 0; j < 8; ++j) x[j] = bf2f(xin[(size_t)e[j].x * 64 + lane]);
#pragma unroll
    for (int j = 0; j < 8; ++j) acc = fmaf(x[j], __int_as_float(e[j].y), acc);
  }
  if (p + 4 <= pe) {
    int2 e[4];
#pragma unroll
    for (int j = 0; j < 4; ++j) e[j] = entries[p + j];
    float x[4];
#pragma unroll
    for (int j = 0; j < 4; ++j) x[j] = bf2f(xin[(size_t)e[j].x * 64 + lane]);
#pragma unroll
    for (int j = 0; j < 4; ++j) acc = fmaf(x[j], __int_as_float(e[j].y), acc);
    p += 4;
  }
  if (p + 2 <= pe) {
    int2 e0 = entries[p], e1 = entries[p + 1];
    float x0 = bf2f(xin[(size_t)e0.x * 64 + lane]);
    float x1 = bf2f(xin[(size_t)e1.x * 64 + lane]);
    acc = fmaf(x0, __int_as_float(e0.y), acc);
    acc = fmaf(x1, __int_as_float(e1.y), acc);
    p += 2;
  }
  if (p < pe) {
    int2 e = entries[p];
    acc = fmaf(bf2f(xin[(size_t)e.x * 64 + lane]), __int_as_float(e.y), acc);
  }
  return acc;
}

// layer-1 aggregation: h1[i][pos ℓ] = relu(b1[pi(ℓ)] + dis[i]*sum) (bf16 out)
__global__ void k_agg(const unsigned short* __restrict__ xin, const int2* __restrict__ entries,
                      const int* __restrict__ offs, const float* __restrict__ dis,
                      const float* __restrict__ bias, unsigned short* __restrict__ xout, int N) {
  const int lane = threadIdx.x & 63;
  const int wv = threadIdx.x >> 6;
  int i = blockIdx.x * 4 + wv;
  if (i >= N) return;
  float acc = row_gather(xin, entries, offs[i], offs[i + 1], lane);
  acc = fmaf(acc, dis[i], bias[permcol(lane)]);
  acc = fmaxf(acc, 0.f);
  xout[(size_t)i * 64 + lane] = f2bf(acc);
}

// masked layer-2 aggregation (no bias/relu; final GEMM adds b2) + emit y[mask]
__global__ void k_agg2m(const unsigned short* __restrict__ xin, const int2* __restrict__ entries,
                        const int* __restrict__ offs, const float* __restrict__ dis,
                        const int* __restrict__ mask, const int* __restrict__ y,
                        float* __restrict__ tout, float* __restrict__ outY, int M) {
  const int lane = threadIdx.x & 63;
  const int wv = threadIdx.x >> 6;
  int o = blockIdx.x * 4 + wv;
  if (o >= M) return;
  int i = mask[o];
  float acc = row_gather(xin, entries, offs[i], offs[i + 1], lane);
  tout[(size_t)o * 64 + lane] = acc * dis[i];
  if (lane == 0) outY[o] = (float)y[i];
}

// final projection [M,64]@[64,64]+b2 via MFMA (permuted-k packed W2), fp32 out
__global__ __launch_bounds__(256) void k_mfma_final(
    const float* __restrict__ X, const unsigned short* __restrict__ packW2,
    const float* __restrict__ b2, float* __restrict__ out, int M) {
  mfma_gemm_body<false, true, false>(X, 64, nullptr, packW2, nullptr, 2, 64,
                                     b2, out, M, blockIdx.x * 4 + (threadIdx.x >> 6));
}

extern "C" void kernel_launch(void* const* d_in, const int* in_sizes, int n_in,
                              void* d_out, int out_size, void* d_ws, size_t ws_size,
                              hipStream_t stream) {
  const float* doc   = (const float*)d_in[0];
  const float* wordf = (const float*)d_in[1];
  const float* ew    = (const float*)d_in[2];
  const float* Wlin  = (const float*)d_in[3];
  const float* blin  = (const float*)d_in[4];
  const float* W1    = (const float*)d_in[5];
  const float* b1    = (const float*)d_in[6];
  const float* W2    = (const float*)d_in[7];
  const float* b2    = (const float*)d_in[8];
  const int*   ei    = (const int*)d_in[9];
  const int*   mask  = (const int*)d_in[10];
  const int*   y     = (const int*)d_in[11];

  const int E  = in_sizes[2];
  const int M  = in_sizes[10];
  const int ND = in_sizes[0] / 768;
  const int NW = in_sizes[1] / 300;
  const int N  = ND + NW;
  const int NE = N + E;

  // workspace carve (aligned 256B)
  char* p = (char*)d_ws;
  auto carve = [&](size_t bytes) -> void* {
    void* q = (void*)p;
    p += (bytes + 255) & ~(size_t)255;
    return q;
  };
  float*          WfuseB = (float*)carve(301 * 64 * 4);
  unsigned short* packW1 = (unsigned short*)carve((size_t)4 * 24 * 64 * 8 * 2);
  unsigned short* packWf = (unsigned short*)carve((size_t)4 * 10 * 64 * 8 * 2);
  unsigned short* packW2 = (unsigned short*)carve((size_t)4 * 2 * 64 * 8 * 2);
  float* dis    = (float*)carve((size_t)N * 4);
  int*   cnt    = (int*)carve((size_t)N * 4);
  int*   offs   = (int*)carve(((size_t)N + 1) * 4);
  int*   cursor = (int*)carve((size_t)N * 4);
  int*   bsum   = (int*)carve(1024);
  int2*  entries = (int2*)carve((size_t)NE * 8);
  unsigned short* xw1 = (unsigned short*)carve((size_t)N * 64 * 2);  // bf16, permuted cols
  unsigned short* h1  = (unsigned short*)carve((size_t)N * 64 * 2);  // bf16, permuted cols
  float* tmask = (float*)carve((size_t)M * 64 * 4);                  // fp32, permuted cols

  hipMemsetAsync(cnt, 0, (size_t)N * 4, stream);

  // phase1: fuse MFMA (strided B) || pack W1 || cnt histogram (4 edges/thr)
  const int fuseBlocks = (301 + 63) / 64;
  const int packBlocks = 24;
  const int cntBlocks  = (E + 1023) / 1024;
  k_phase1<<<fuseBlocks + packBlocks + cntBlocks, 256, 0, stream>>>(
      Wlin, blin, W1, WfuseB, packW1, ei, E, cnt, fuseBlocks, packBlocks);

  int nb = (N + 1023) / 1024;
  k_scan_reduce<<<nb + 12, 256, 0, stream>>>(cnt, N, bsum, WfuseB, packWf, W2, packW2, nb);
  k_scan_small<<<1, 128, 0, stream>>>(bsum, nb);
  k_scan_final<<<nb, 256, 0, stream>>>(cnt, N, bsum, offs, cursor, entries);

  // CSR fill (separate dispatch for attribution)
  k_fill<<<(E + 1023) / 1024, 256, 0, stream>>>(ei, ew, E, cursor, entries);

  // degdis || doc MFMA || word MFMA
  const int degBlocks  = (N + 255) / 256;
  const int docBlocks  = (ND + 63) / 64;
  const int wordBlocks = (NW + 63) / 64;
  k_gemms<<<degBlocks + docBlocks + wordBlocks, 256, 0, stream>>>(
      entries, offs, dis, N, degBlocks,
      doc, packW1, xw1, ND, docBlocks,
      wordf, packWf, WfuseB + (size_t)300 * 64, xw1 + (size_t)ND * 64, NW);

  k_prenorm<<<(NE + 255) / 256, 256, 0, stream>>>(entries, dis, NE);

  // layer-1 aggregation (+b1 via pi, relu) -> bf16 h1 (permuted)
  k_agg<<<(N + 3) / 4, 256, 0, stream>>>(xw1, entries, offs, dis, b1, h1, N);

  // layer-2: masked aggregation over h1, then project [M,64]@[64,64]+b2
  float* out0 = (float*)d_out;
  float* outY = out0 + (size_t)M * 64;
  k_agg2m<<<(M + 3) / 4, 256, 0, stream>>>(h1, entries, offs, dis, mask, y, tmask, outY, M);
  k_mfma_final<<<(M + 63) / 64, 256, 0, stream>>>(tmask, packW2, b2, out0, M);
}

// Round 9
// 402.851 us; speedup vs baseline: 1.1051x; 1.0436x over previous
//
#include <hip/hip_runtime.h>

// ---------------------------------------------------------------------------
// TextGCN (2-layer GCN, eval mode) on MI355X.
// Fusions:
//   * xw1_word = word @ (W_lin@W1) + (b_lin@W1)  (never materialize [N,768] x)
//   * layer 2: agg(h1@W2)[mask] == agg(h1)[mask] @ W2
// CSR holds RAW weights at build; degdis computes dis; prenorm folds dis[src]
// into entries.y. Self-loop has reserved slot offs[i] (no atomic).
// xw1/h1 stored bf16 in PERMUTED column order pi(pos)=(pos&3)*16+(pos>>2) so
// MFMA epilogue stores are 4x coalesced 8B. b1 indexed via pi; packW2 k-rows
// permuted via pi so the final MFMA consumes permuted tmask directly.
// MFMA GEMM software-pipelines BOTH A-rows and B-fragments (double-buffered
// registers, no LDS/barriers). Agg kernels use HALF-WAVE per node (32 lanes x
// ushort2) -> 2 nodes/wave, 2x per-CU outstanding gathers.
// Dispatches: phase1(fuse||packW1||cnt) -> scans -> k_fill -> k_gemms(degdis
// || docMFMA || wordMFMA) -> prenorm -> agg -> agg2m -> final.
// ---------------------------------------------------------------------------

typedef __attribute__((ext_vector_type(8))) short short8;   // 8 bf16 = 4 VGPR
typedef __attribute__((ext_vector_type(4))) float float4v;  // MFMA C/D frag

__device__ __forceinline__ unsigned short f2bf(float f) {   // RNE f32->bf16
  unsigned u = __float_as_uint(f);
  return (unsigned short)((u + 0x7FFFu + ((u >> 16) & 1u)) >> 16);
}
__device__ __forceinline__ float bf2f(unsigned short u) {
  return __uint_as_float((unsigned)u << 16);
}
__device__ __forceinline__ int permcol(int p) {   // pi: pos -> true col
  return ((p & 3) << 4) | (p >> 2);
}

// pack W[K,64] fp32 -> bf16 fragment order: pack[((g*nk0+k0)*64+lane)*8+j]
// holds W[ksrc][(lane&15)+16g], ksrc = PERM ? pi(k) : k; zero past K.
template <bool PERM>
__device__ __forceinline__ void pack_w_body(const float* __restrict__ W, int K,
                                            int nk0, unsigned short* __restrict__ pack,
                                            int tid) {
  int lane = tid & 63;
  int rest = tid >> 6;
  int k0 = rest % nk0;
  int g = rest / nk0;
  int quad = lane >> 4;
  int n = (lane & 15) + g * 16;
  short8 v;
#pragma unroll
  for (int j = 0; j < 8; ++j) {
    int k = k0 * 32 + quad * 8 + j;
    int ks = PERM ? permcol(k) : k;
    float w = (k < K) ? W[(size_t)ks * 64 + n] : 0.f;
    v[j] = (short)f2bf(w);
  }
  *(short8*)(pack + (((size_t)(g * nk0 + k0) * 64 + lane) << 3)) = v;
}

// MFMA GEMM: out[R,64] = X[R,K(ldx)] @ W[K,64] (+bias). One wave = 16 rows.
// A-rows AND B-fragments register-prefetched one k0 ahead (no LDS/barriers).
template <bool LAST, bool PACKED, bool BF16PERM>
__device__ __forceinline__ void mfma_gemm_body(
    const float* __restrict__ X, int ldx, const float* __restrict__ lastRow,
    const unsigned short* __restrict__ Wpack, const float* __restrict__ Wf,
    int nk0, int K, const float* __restrict__ bias,
    void* __restrict__ outv, int R, int waveIdx) {
  int r0 = waveIdx * 16;
  if (r0 >= R) return;
  const int lane = threadIdx.x & 63;
  const int quad = lane >> 4;
  const int m = lane & 15;
  const int row = r0 + m;
  const float* xrow = nullptr;
  if (row < R) xrow = (LAST && row == R - 1) ? lastRow : X + (size_t)row * ldx;

  float4v acc[4];
#pragma unroll
  for (int g = 0; g < 4; ++g) acc[g] = (float4v){0.f, 0.f, 0.f, 0.f};

  auto loadA = [&](int k0, float* a) {
    int kb = k0 * 32 + quad * 8;
    if (xrow && kb + 8 <= K) {
      float4 v0 = *(const float4*)(xrow + kb);
      float4 v1 = *(const float4*)(xrow + kb + 4);
      a[0] = v0.x; a[1] = v0.y; a[2] = v0.z; a[3] = v0.w;
      a[4] = v1.x; a[5] = v1.y; a[6] = v1.z; a[7] = v1.w;
    } else {
#pragma unroll
      for (int j = 0; j < 8; ++j) {
        int k = kb + j;
        a[j] = (xrow && k < K) ? xrow[k] : 0.f;
      }
    }
  };
  auto loadB = [&](int k0, short8* bf) {
#pragma unroll
    for (int g = 0; g < 4; ++g) {
      if (PACKED) {
        bf[g] = *(const short8*)(Wpack + (((size_t)(g * nk0 + k0) * 64 + lane) << 3));
      } else {
        int kb = k0 * 32 + quad * 8;
        int n = g * 16 + m;
#pragma unroll
        for (int j = 0; j < 8; ++j) {
          int k = kb + j;
          float w = (k < K) ? Wf[(size_t)k * 64 + n] : 0.f;
          bf[g][j] = (short)f2bf(w);
        }
      }
    }
  };
  auto compute = [&](const float* a, const short8* bf) {
    short8 af;
#pragma unroll
    for (int j = 0; j < 8; ++j) af[j] = (short)f2bf(a[j]);
#pragma unroll
    for (int g = 0; g < 4; ++g)
      acc[g] = __builtin_amdgcn_mfma_f32_16x16x32_bf16(af, bf[g], acc[g], 0, 0, 0);
  };

  float aA[8], aB[8];
  short8 bA[4], bB[4];
  loadA(0, aA); loadB(0, bA);
  for (int k0 = 0; k0 < nk0; k0 += 2) {
    if (k0 + 1 < nk0) { loadA(k0 + 1, aB); loadB(k0 + 1, bB); }
    compute(aA, bA);
    if (k0 + 1 >= nk0) break;
    if (k0 + 2 < nk0) { loadA(k0 + 2, aA); loadB(k0 + 2, bA); }
    compute(aB, bB);
  }

  if (BF16PERM) {
    // lane m packs cols {m,16+m,32+m,48+m} of row r0+quad*4+j as 4 bf16 (8B)
    float b0 = bias ? bias[m] : 0.f;
    float b1 = bias ? bias[16 + m] : 0.f;
    float b2 = bias ? bias[32 + m] : 0.f;
    float b3 = bias ? bias[48 + m] : 0.f;
#pragma unroll
    for (int j = 0; j < 4; ++j) {
      int r = r0 + quad * 4 + j;
      if (r < R) {
        ushort4 pk;
        pk.x = f2bf(acc[0][j] + b0);
        pk.y = f2bf(acc[1][j] + b1);
        pk.z = f2bf(acc[2][j] + b2);
        pk.w = f2bf(acc[3][j] + b3);
        *(ushort4*)((unsigned short*)outv + ((size_t)r * 64 + m * 4)) = pk;
      }
    }
  } else {
#pragma unroll
    for (int g = 0; g < 4; ++g) {
      float b = bias ? bias[g * 16 + m] : 0.f;
#pragma unroll
      for (int reg = 0; reg < 4; ++reg) {
        int r = r0 + quad * 4 + reg;    // C/D: col=lane&15, row=quad*4+reg
        if (r < R) ((float*)outv)[(size_t)r * 64 + g * 16 + m] = acc[g][reg] + b;
      }
    }
  }
}

// phase1: [fuseBlocks) fuse GEMM [Wlin;blin]@W1 -> WfuseB (strided fp32 B);
//         [+packBlocks) pack W1; rest: cnt histogram, 4 edges/thread.
__global__ __launch_bounds__(256) void k_phase1(
    const float* __restrict__ Wlin, const float* __restrict__ blin,
    const float* __restrict__ W1, float* __restrict__ WfuseB,
    unsigned short* __restrict__ packW1,
    const int* __restrict__ ei, int E, int* __restrict__ cnt,
    int fuseBlocks, int packBlocks) {
  int b = blockIdx.x;
  if (b < fuseBlocks) {
    mfma_gemm_body<true, false, false>(Wlin, 768, blin, nullptr, W1, 24, 768,
                                       nullptr, WfuseB, 301, b * 4 + (threadIdx.x >> 6));
    return;
  }
  b -= fuseBlocks;
  if (b < packBlocks) {
    pack_w_body<false>(W1, 768, 24, packW1, b * 256 + threadIdx.x);
    return;
  }
  b -= packBlocks;
  int e0 = (b * 256 + threadIdx.x) * 4;
#pragma unroll
  for (int j = 0; j < 4; ++j) {
    int e = e0 + j;
    if (e < E) atomicAdd(cnt + ei[E + e], 1);   // fire-and-forget
  }
}

// ---- scan of (cnt[i]+1) -> offs[N+1]; also packs Wfuse & W2(permuted) ----
__global__ void k_scan_reduce(const int* __restrict__ cnt, int N, int* __restrict__ bsum,
                              const float* __restrict__ WfuseB, unsigned short* __restrict__ packWf,
                              const float* __restrict__ W2, unsigned short* __restrict__ packW2,
                              int nb) {
  int b = blockIdx.x, t = threadIdx.x;
  if (b >= nb) {
    b -= nb;
    if (b < 10) pack_w_body<false>(WfuseB, 300, 10, packWf, b * 256 + t);
    else pack_w_body<true>(W2, 64, 2, packW2, (b - 10) * 256 + t);
    return;
  }
  __shared__ int sd[256];
  int base = b * 1024 + t * 4;
  int s = 0;
#pragma unroll
  for (int j = 0; j < 4; ++j) s += (base + j < N) ? cnt[base + j] + 1 : 0;
  sd[t] = s; __syncthreads();
  for (int off = 128; off > 0; off >>= 1) {
    if (t < off) sd[t] += sd[t + off];
    __syncthreads();
  }
  if (t == 0) bsum[b] = sd[0];
}

__global__ void k_scan_small(int* __restrict__ bsum, int nb) {
  __shared__ int s[128];
  int t = threadIdx.x;
  int v = (t < nb) ? bsum[t] : 0;
  s[t] = v; __syncthreads();
  for (int off = 1; off < 128; off <<= 1) {
    int x = (t >= off) ? s[t - off] : 0;
    __syncthreads();
    s[t] += x;
    __syncthreads();
  }
  if (t < nb) bsum[t] = s[t] - v;   // exclusive
}

__global__ void k_scan_final(const int* __restrict__ cnt, int N, const int* __restrict__ bsum,
                             int* __restrict__ offs, int* __restrict__ cursor,
                             int2* __restrict__ entries) {
  __shared__ int sd[256];
  int b = blockIdx.x, t = threadIdx.x;
  int base = b * 1024 + t * 4;
  int v[4], loc = 0;
#pragma unroll
  for (int j = 0; j < 4; ++j) { v[j] = (base + j < N) ? cnt[base + j] + 1 : 0; loc += v[j]; }
  sd[t] = loc; __syncthreads();
  for (int off = 1; off < 256; off <<= 1) {
    int x = (t >= off) ? sd[t - off] : 0;
    __syncthreads();
    sd[t] += x;
    __syncthreads();
  }
  int run = bsum[b] + sd[t] - loc;
#pragma unroll
  for (int j = 0; j < 4; ++j) {
    if (base + j < N) {
      int i = base + j;
      offs[i] = run;
      cursor[i] = run + 1;                               // slot 0 = self loop
      entries[run] = make_int2(i, __float_as_int(1.0f)); // raw w=1
      run += v[j];
    }
  }
  if (b == gridDim.x - 1 && t == 255) offs[N] = run;  // total = N + E
}

// CSR fill only (4 edges/thread, 4 independent atomic chains)
__global__ __launch_bounds__(256) void k_fill(
    const int* __restrict__ ei, const float* __restrict__ ew, int E,
    int* __restrict__ cursor, int2* __restrict__ entries) {
  int e0 = (blockIdx.x * 256 + threadIdx.x) * 4;
  int src[4], dst[4];
  float w[4];
#pragma unroll
  for (int j = 0; j < 4; ++j) {
    int e = e0 + j;
    if (e < E) { src[j] = ei[e]; dst[j] = ei[E + e]; w[j] = ew[e]; }
  }
  int pos[4];
#pragma unroll
  for (int j = 0; j < 4; ++j)
    if (e0 + j < E) pos[j] = atomicAdd(cursor + dst[j], 1);
#pragma unroll
  for (int j = 0; j < 4; ++j)
    if (e0 + j < E) entries[pos[j]] = make_int2(src[j], __float_as_int(w[j]));
}

// k_gemms: [degBlocks) deg->dis (atomic-free); [+docBlocks) doc MFMA; rest word.
__global__ __launch_bounds__(256) void k_gemms(
    const int2* __restrict__ entries, const int* __restrict__ offs,
    float* __restrict__ dis, int N, int degBlocks,
    const float* __restrict__ doc, const unsigned short* __restrict__ packW1,
    unsigned short* __restrict__ xw1, int ND, int docBlocks,
    const float* __restrict__ wordf, const unsigned short* __restrict__ packWf,
    const float* __restrict__ bfuse, unsigned short* __restrict__ xw1word, int NW) {
  int b = blockIdx.x;
  if (b < degBlocks) {
    int i = b * 256 + threadIdx.x;
    if (i >= N) return;
    int p = offs[i], pe = offs[i + 1];
    float d = 0.f;
    for (; p < pe; ++p) d += __int_as_float(entries[p].y);
    dis[i] = d > 0.f ? rsqrtf(fmaxf(d, 1e-12f)) : 0.f;
    return;
  }
  b -= degBlocks;
  if (b < docBlocks) {
    mfma_gemm_body<false, true, true>(doc, 768, nullptr, packW1, nullptr, 24, 768,
                                      nullptr, xw1, ND, b * 4 + (threadIdx.x >> 6));
  } else {
    b -= docBlocks;
    mfma_gemm_body<false, true, true>(wordf, 300, nullptr, packWf, nullptr, 10, 300,
                                      bfuse, xw1word, NW, b * 4 + (threadIdx.x >> 6));
  }
}

// fold dis[src] into entries.y (sequential r/m/w, coalesced)
__global__ void k_prenorm(int2* __restrict__ entries, const float* __restrict__ dis, int NE) {
  int p = blockIdx.x * blockDim.x + threadIdx.x;
  if (p >= NE) return;
  int2 e = entries[p];
  entries[p].y = __float_as_int(__int_as_float(e.y) * dis[e.x]);
}

// half-wave gather-accumulate: 32 lanes, each lane covers 2 cols (ushort2).
// Prenormed weights; 8/4/2/1 tail ladder.
__device__ __forceinline__ void row_gather2(const unsigned short* __restrict__ xin,
                                            const int2* __restrict__ entries,
                                            int p, int pe, int l32,
                                            float& ra0, float& ra1) {
  float a0 = 0.f, a1 = 0.f;
  for (; p + 8 <= pe; p += 8) {
    int2 e[8];
#pragma unroll
    for (int j = 0; j < 8; ++j) e[j] = entries[p + j];
    unsigned x[8];
#pragma unroll
    for (int j = 0; j < 8; ++j)
      x[j] = *(const unsigned*)(xin + ((size_t)e[j].x << 6) + (l32 << 1));
#pragma unroll
    for (int j = 0; j < 8; ++j) {
      float w = __int_as_float(e[j].y);
      a0 = fmaf(bf2f((unsigned short)(x[j] & 0xffffu)), w, a0);
      a1 = fmaf(bf2f((unsigned short)(x[j] >> 16)), w, a1);
    }
  }
  if (p + 4 <= pe) {
    int2 e[4];
#pragma unroll
    for (int j = 0; j < 4; ++j) e[j] = entries[p + j];
    unsigned x[4];
#pragma unroll
    for (int j = 0; j < 4; ++j)
      x[j] = *(const unsigned*)(xin + ((size_t)e[j].x << 6) + (l32 << 1));
#pragma unroll
    for (int j = 0; j < 4; ++j) {
      float w = __int_as_float(e[j].y);
      a0 = fmaf(bf2f((unsigned short)(x[j] & 0xffffu)), w, a0);
      a1 = fmaf(bf2f((unsigned short)(x[j] >> 16)), w, a1);
    }
    p += 4;
  }
  if (p + 2 <= pe) {
    int2 e0 = entries[p], e1 = entries[p + 1];
    unsigned x0 = *(const unsigned*)(xin + ((size_t)e0.x << 6) + (l32 << 1));
    unsigned x1 = *(const unsigned*)(xin + ((size_t)e1.x << 6) + (l32 << 1));
    float w0 = __int_as_float(e0.y), w1 = __int_as_float(e1.y);
    a0 = fmaf(bf2f((unsigned short)(x0 & 0xffffu)), w0, a0);
    a1 = fmaf(bf2f((unsigned short)(x0 >> 16)), w0, a1);
    a0 = fmaf(bf2f((unsigned short)(x1 & 0xffffu)), w1, a0);
    a1 = fmaf(bf2f((unsigned short)(x1 >> 16)), w1, a1);
    p += 2;
  }
  if (p < pe) {
    int2 e = entries[p];
    unsigned x = *(const unsigned*)(xin + ((size_t)e.x << 6) + (l32 << 1));
    float w = __int_as_float(e.y);
    a0 = fmaf(bf2f((unsigned short)(x & 0xffffu)), w, a0);
    a1 = fmaf(bf2f((unsigned short)(x >> 16)), w, a1);
  }
  ra0 = a0; ra1 = a1;
}

// layer-1 aggregation: half-wave per node, ushort2 out (permuted pos layout)
__global__ void k_agg(const unsigned short* __restrict__ xin, const int2* __restrict__ entries,
                      const int* __restrict__ offs, const float* __restrict__ dis,
                      const float* __restrict__ bias, unsigned short* __restrict__ xout, int N) {
  const int tid = threadIdx.x;
  const int l32 = tid & 31;
  int i = blockIdx.x * 8 + (tid >> 5);
  if (i >= N) return;
  float a0, a1;
  row_gather2(xin, entries, offs[i], offs[i + 1], l32, a0, a1);
  float d = dis[i];
  a0 = fmaf(a0, d, bias[permcol(2 * l32)]);
  a1 = fmaf(a1, d, bias[permcol(2 * l32 + 1)]);
  a0 = fmaxf(a0, 0.f);
  a1 = fmaxf(a1, 0.f);
  ushort2 pk;
  pk.x = f2bf(a0);
  pk.y = f2bf(a1);
  *(ushort2*)(xout + ((size_t)i << 6) + (l32 << 1)) = pk;
}

// masked layer-2 aggregation: half-wave per masked node, fp32 out + y[mask]
__global__ void k_agg2m(const unsigned short* __restrict__ xin, const int2* __restrict__ entries,
                        const int* __restrict__ offs, const float* __restrict__ dis,
                        const int* __restrict__ mask, const int* __restrict__ y,
                        float* __restrict__ tout, float* __restrict__ outY, int M) {
  const int tid = threadIdx.x;
  const int l32 = tid & 31;
  int o = blockIdx.x * 8 + (tid >> 5);
  if (o >= M) return;
  int i = mask[o];
  float a0, a1;
  row_gather2(xin, entries, offs[i], offs[i + 1], l32, a0, a1);
  float d = dis[i];
  float2 pk;
  pk.x = a0 * d;
  pk.y = a1 * d;
  *(float2*)(tout + ((size_t)o << 6) + (l32 << 1)) = pk;
  if (l32 == 0) outY[o] = (float)y[i];
}

// final projection [M,64]@[64,64]+b2 via MFMA (permuted-k packed W2), fp32 out
__global__ __launch_bounds__(256) void k_mfma_final(
    const float* __restrict__ X, const unsigned short* __restrict__ packW2,
    const float* __restrict__ b2, float* __restrict__ out, int M) {
  mfma_gemm_body<false, true, false>(X, 64, nullptr, packW2, nullptr, 2, 64,
                                     b2, out, M, blockIdx.x * 4 + (threadIdx.x >> 6));
}

extern "C" void kernel_launch(void* const* d_in, const int* in_sizes, int n_in,
                              void* d_out, int out_size, void* d_ws, size_t ws_size,
                              hipStream_t stream) {
  const float* doc   = (const float*)d_in[0];
  const float* wordf = (const float*)d_in[1];
  const float* ew    = (const float*)d_in[2];
  const float* Wlin  = (const float*)d_in[3];
  const float* blin  = (const float*)d_in[4];
  const float* W1    = (const float*)d_in[5];
  const float* b1    = (const float*)d_in[6];
  const float* W2    = (const float*)d_in[7];
  const float* b2    = (const float*)d_in[8];
  const int*   ei    = (const int*)d_in[9];
  const int*   mask  = (const int*)d_in[10];
  const int*   y     = (const int*)d_in[11];

  const int E  = in_sizes[2];
  const int M  = in_sizes[10];
  const int ND = in_sizes[0] / 768;
  const int NW = in_sizes[1] / 300;
  const int N  = ND + NW;
  const int NE = N + E;

  // workspace carve (aligned 256B)
  char* p = (char*)d_ws;
  auto carve = [&](size_t bytes) -> void* {
    void* q = (void*)p;
    p += (bytes + 255) & ~(size_t)255;
    return q;
  };
  float*          WfuseB = (float*)carve(301 * 64 * 4);
  unsigned short* packW1 = (unsigned short*)carve((size_t)4 * 24 * 64 * 8 * 2);
  unsigned short* packWf = (unsigned short*)carve((size_t)4 * 10 * 64 * 8 * 2);
  unsigned short* packW2 = (unsigned short*)carve((size_t)4 * 2 * 64 * 8 * 2);
  float* dis    = (float*)carve((size_t)N * 4);
  int*   cnt    = (int*)carve((size_t)N * 4);
  int*   offs   = (int*)carve(((size_t)N + 1) * 4);
  int*   cursor = (int*)carve((size_t)N * 4);
  int*   bsum   = (int*)carve(1024);
  int2*  entries = (int2*)carve((size_t)NE * 8);
  unsigned short* xw1 = (unsigned short*)carve((size_t)N * 64 * 2);  // bf16, permuted cols
  unsigned short* h1  = (unsigned short*)carve((size_t)N * 64 * 2);  // bf16, permuted cols
  float* tmask = (float*)carve((size_t)M * 64 * 4);                  // fp32, permuted cols

  hipMemsetAsync(cnt, 0, (size_t)N * 4, stream);

  // phase1: fuse MFMA (strided B) || pack W1 || cnt histogram (4 edges/thr)
  const int fuseBlocks = (301 + 63) / 64;
  const int packBlocks = 24;
  const int cntBlocks  = (E + 1023) / 1024;
  k_phase1<<<fuseBlocks + packBlocks + cntBlocks, 256, 0, stream>>>(
      Wlin, blin, W1, WfuseB, packW1, ei, E, cnt, fuseBlocks, packBlocks);

  int nb = (N + 1023) / 1024;
  k_scan_reduce<<<nb + 12, 256, 0, stream>>>(cnt, N, bsum, WfuseB, packWf, W2, packW2, nb);
  k_scan_small<<<1, 128, 0, stream>>>(bsum, nb);
  k_scan_final<<<nb, 256, 0, stream>>>(cnt, N, bsum, offs, cursor, entries);

  // CSR fill
  k_fill<<<(E + 1023) / 1024, 256, 0, stream>>>(ei, ew, E, cursor, entries);

  // degdis || doc MFMA || word MFMA
  const int degBlocks  = (N + 255) / 256;
  const int docBlocks  = (ND + 63) / 64;
  const int wordBlocks = (NW + 63) / 64;
  k_gemms<<<degBlocks + docBlocks + wordBlocks, 256, 0, stream>>>(
      entries, offs, dis, N, degBlocks,
      doc, packW1, xw1, ND, docBlocks,
      wordf, packWf, WfuseB + (size_t)300 * 64, xw1 + (size_t)ND * 64, NW);

  k_prenorm<<<(NE + 255) / 256, 256, 0, stream>>>(entries, dis, NE);

  // layer-1 aggregation (+b1 via pi, relu) -> bf16 h1 (permuted)
  k_agg<<<(N + 7) / 8, 256, 0, stream>>>(xw1, entries, offs, dis, b1, h1, N);

  // layer-2: masked aggregation over h1, then project [M,64]@[64,64]+b2
  float* out0 = (float*)d_out;
  float* outY = out0 + (size_t)M * 64;
  k_agg2m<<<(M + 7) / 8, 256, 0, stream>>>(h1, entries, offs, dis, mask, y, tmask, outY, M);
  k_mfma_final<<<(M + 63) / 64, 256, 0, stream>>>(tmask, packW2, b2, out0, M);
}

// Round 10
// 398.910 us; speedup vs baseline: 1.1161x; 1.0099x over previous
//
#include <hip/hip_runtime.h>

// ---------------------------------------------------------------------------
// TextGCN (2-layer GCN, eval mode) on MI355X.
// Fusions:
//   * xw1_word = word @ (W_lin@W1) + (b_lin@W1)  (never materialize [N,768] x)
//   * layer 2: agg(h1@W2)[mask] == agg(h1)[mask] @ W2
// CSR holds RAW weights at build; degdis computes dis; prenorm folds dis[src]
// into entries.y. Self-loop has reserved slot offs[i] (no atomic).
// xw1/h1 bf16 in PERMUTED column order pi(pos)=(pos&3)*16+(pos>>2) (coalesced
// 8B MFMA epilogue stores). b1 indexed via pi; packW2 k-rows permuted via pi.
// MFMA GEMM: 32 rows/wave (2 rowsets SHARE each B-fragment load -> half the
// B re-read traffic), no LDS/barriers.
// Order: k_pre(fuse||packW1||packW2) -> k_main(docMFMA||wordMFMA||cnt) ->
// scans -> fill -> degdis -> prenorm -> agg -> agg2m -> final.
// (cnt histogram hidden under the BW-bound GEMMs; word-B read strided fp32
// from WfuseB so no packWf dependency.)
// ---------------------------------------------------------------------------

typedef __attribute__((ext_vector_type(8))) short short8;   // 8 bf16 = 4 VGPR
typedef __attribute__((ext_vector_type(4))) float float4v;  // MFMA C/D frag

__device__ __forceinline__ unsigned short f2bf(float f) {   // RNE f32->bf16
  unsigned u = __float_as_uint(f);
  return (unsigned short)((u + 0x7FFFu + ((u >> 16) & 1u)) >> 16);
}
__device__ __forceinline__ float bf2f(unsigned short u) {
  return __uint_as_float((unsigned)u << 16);
}
__device__ __forceinline__ int permcol(int p) {   // pi: pos -> true col
  return ((p & 3) << 4) | (p >> 2);
}

// pack W[K,64] fp32 -> bf16 fragment order: pack[((g*nk0+k0)*64+lane)*8+j]
// holds W[ksrc][(lane&15)+16g], ksrc = PERM ? pi(k) : k; zero past K.
template <bool PERM>
__device__ __forceinline__ void pack_w_body(const float* __restrict__ W, int K,
                                            int nk0, unsigned short* __restrict__ pack,
                                            int tid) {
  int lane = tid & 63;
  int rest = tid >> 6;
  int k0 = rest % nk0;
  int g = rest / nk0;
  int quad = lane >> 4;
  int n = (lane & 15) + g * 16;
  short8 v;
#pragma unroll
  for (int j = 0; j < 8; ++j) {
    int k = k0 * 32 + quad * 8 + j;
    int ks = PERM ? permcol(k) : k;
    float w = (k < K) ? W[(size_t)ks * 64 + n] : 0.f;
    v[j] = (short)f2bf(w);
  }
  *(short8*)(pack + (((size_t)(g * nk0 + k0) * 64 + lane) << 3)) = v;
}

// MFMA GEMM: out[R,64] = X[R,K(ldx)] @ W[K,64] (+bias). One wave = 16*RS rows;
// RS rowsets share each B-fragment load (halves B traffic at RS=2).
template <bool LAST, bool PACKED, bool BF16PERM, int RS>
__device__ __forceinline__ void mfma_gemm_body(
    const float* __restrict__ X, int ldx, const float* __restrict__ lastRow,
    const unsigned short* __restrict__ Wpack, const float* __restrict__ Wf,
    int nk0, int K, const float* __restrict__ bias,
    void* __restrict__ outv, int R, int waveIdx) {
  int r0 = waveIdx * 16 * RS;
  if (r0 >= R) return;
  const int lane = threadIdx.x & 63;
  const int quad = lane >> 4;
  const int m = lane & 15;
  const float* xrow[RS];
#pragma unroll
  for (int rs = 0; rs < RS; ++rs) {
    int row = r0 + rs * 16 + m;
    xrow[rs] = nullptr;
    if (row < R) xrow[rs] = (LAST && row == R - 1) ? lastRow : X + (size_t)row * ldx;
  }

  float4v acc[RS][4];
#pragma unroll
  for (int rs = 0; rs < RS; ++rs)
#pragma unroll
    for (int g = 0; g < 4; ++g) acc[rs][g] = (float4v){0.f, 0.f, 0.f, 0.f};

  for (int k0 = 0; k0 < nk0; ++k0) {
    int kb = k0 * 32 + quad * 8;
    float a[RS][8];
#pragma unroll
    for (int rs = 0; rs < RS; ++rs) {
      if (xrow[rs] && kb + 8 <= K) {
        float4 v0 = *(const float4*)(xrow[rs] + kb);
        float4 v1 = *(const float4*)(xrow[rs] + kb + 4);
        a[rs][0] = v0.x; a[rs][1] = v0.y; a[rs][2] = v0.z; a[rs][3] = v0.w;
        a[rs][4] = v1.x; a[rs][5] = v1.y; a[rs][6] = v1.z; a[rs][7] = v1.w;
      } else {
#pragma unroll
        for (int j = 0; j < 8; ++j) {
          int k = kb + j;
          a[rs][j] = (xrow[rs] && k < K) ? xrow[rs][k] : 0.f;
        }
      }
    }
    short8 bf[4];
#pragma unroll
    for (int g = 0; g < 4; ++g) {
      if (PACKED) {
        bf[g] = *(const short8*)(Wpack + (((size_t)(g * nk0 + k0) * 64 + lane) << 3));
      } else {
        int n = g * 16 + m;
#pragma unroll
        for (int j = 0; j < 8; ++j) {
          int k = kb + j;
          float w = (k < K) ? Wf[(size_t)k * 64 + n] : 0.f;
          bf[g][j] = (short)f2bf(w);
        }
      }
    }
#pragma unroll
    for (int rs = 0; rs < RS; ++rs) {
      short8 af;
#pragma unroll
      for (int j = 0; j < 8; ++j) af[j] = (short)f2bf(a[rs][j]);
#pragma unroll
      for (int g = 0; g < 4; ++g)
        acc[rs][g] = __builtin_amdgcn_mfma_f32_16x16x32_bf16(af, bf[g], acc[rs][g], 0, 0, 0);
    }
  }

#pragma unroll
  for (int rs = 0; rs < RS; ++rs) {
    int rb = r0 + rs * 16;
    if (BF16PERM) {
      // lane m packs cols {m,16+m,32+m,48+m} of row rb+quad*4+j as 4 bf16 (8B)
      float b0 = bias ? bias[m] : 0.f;
      float b1 = bias ? bias[16 + m] : 0.f;
      float b2 = bias ? bias[32 + m] : 0.f;
      float b3 = bias ? bias[48 + m] : 0.f;
#pragma unroll
      for (int j = 0; j < 4; ++j) {
        int r = rb + quad * 4 + j;
        if (r < R) {
          ushort4 pk;
          pk.x = f2bf(acc[rs][0][j] + b0);
          pk.y = f2bf(acc[rs][1][j] + b1);
          pk.z = f2bf(acc[rs][2][j] + b2);
          pk.w = f2bf(acc[rs][3][j] + b3);
          *(ushort4*)((unsigned short*)outv + ((size_t)r * 64 + m * 4)) = pk;
        }
      }
    } else {
#pragma unroll
      for (int g = 0; g < 4; ++g) {
        float b = bias ? bias[g * 16 + m] : 0.f;
#pragma unroll
        for (int reg = 0; reg < 4; ++reg) {
          int r = rb + quad * 4 + reg;   // C/D: col=lane&15, row=quad*4+reg
          if (r < R) ((float*)outv)[(size_t)r * 64 + g * 16 + m] = acc[rs][g][reg] + b;
        }
      }
    }
  }
}

// k_pre: [fuseBlocks) fuse GEMM [Wlin;blin]@W1 -> WfuseB (strided fp32 B);
//        [+24) pack W1; [+2) pack W2 (permuted k).
__global__ __launch_bounds__(256) void k_pre(
    const float* __restrict__ Wlin, const float* __restrict__ blin,
    const float* __restrict__ W1, float* __restrict__ WfuseB,
    unsigned short* __restrict__ packW1,
    const float* __restrict__ W2, unsigned short* __restrict__ packW2,
    int fuseBlocks) {
  int b = blockIdx.x;
  if (b < fuseBlocks) {
    mfma_gemm_body<true, false, false, 2>(Wlin, 768, blin, nullptr, W1, 24, 768,
                                          nullptr, WfuseB, 301, b * 4 + (threadIdx.x >> 6));
    return;
  }
  b -= fuseBlocks;
  if (b < 24) { pack_w_body<false>(W1, 768, 24, packW1, b * 256 + threadIdx.x); return; }
  b -= 24;
  pack_w_body<true>(W2, 64, 2, packW2, b * 256 + threadIdx.x);
}

// k_main: [docBlocks) doc MFMA (packed W1); [+wordBlocks) word MFMA (strided
// fp32 WfuseB); rest: cnt histogram (4 edges/thread, fire-and-forget atomics).
__global__ __launch_bounds__(256) void k_main(
    const float* __restrict__ doc, const unsigned short* __restrict__ packW1,
    unsigned short* __restrict__ xw1, int ND, int docBlocks,
    const float* __restrict__ wordf, const float* __restrict__ WfuseB,
    const float* __restrict__ bfuse, unsigned short* __restrict__ xw1word,
    int NW, int wordBlocks,
    const int* __restrict__ ei, int E, int* __restrict__ cnt) {
  int b = blockIdx.x;
  if (b < docBlocks) {
    mfma_gemm_body<false, true, true, 2>(doc, 768, nullptr, packW1, nullptr, 24, 768,
                                         nullptr, xw1, ND, b * 4 + (threadIdx.x >> 6));
    return;
  }
  b -= docBlocks;
  if (b < wordBlocks) {
    mfma_gemm_body<false, false, true, 2>(wordf, 300, nullptr, nullptr, WfuseB, 10, 300,
                                          bfuse, xw1word, NW, b * 4 + (threadIdx.x >> 6));
    return;
  }
  b -= wordBlocks;
  int e0 = (b * 256 + threadIdx.x) * 4;
#pragma unroll
  for (int j = 0; j < 4; ++j) {
    int e = e0 + j;
    if (e < E) atomicAdd(cnt + ei[E + e], 1);
  }
}

// ---- 3-kernel exclusive scan of (cnt[i]+1) -> offs[N+1]; self-loop entry ----
__global__ void k_scan_reduce(const int* __restrict__ cnt, int N, int* __restrict__ bsum) {
  __shared__ int sd[256];
  int b = blockIdx.x, t = threadIdx.x;
  int base = b * 1024 + t * 4;
  int s = 0;
#pragma unroll
  for (int j = 0; j < 4; ++j) s += (base + j < N) ? cnt[base + j] + 1 : 0;
  sd[t] = s; __syncthreads();
  for (int off = 128; off > 0; off >>= 1) {
    if (t < off) sd[t] += sd[t + off];
    __syncthreads();
  }
  if (t == 0) bsum[b] = sd[0];
}

__global__ void k_scan_small(int* __restrict__ bsum, int nb) {
  __shared__ int s[128];
  int t = threadIdx.x;
  int v = (t < nb) ? bsum[t] : 0;
  s[t] = v; __syncthreads();
  for (int off = 1; off < 128; off <<= 1) {
    int x = (t >= off) ? s[t - off] : 0;
    __syncthreads();
    s[t] += x;
    __syncthreads();
  }
  if (t < nb) bsum[t] = s[t] - v;   // exclusive
}

__global__ void k_scan_final(const int* __restrict__ cnt, int N, const int* __restrict__ bsum,
                             int* __restrict__ offs, int* __restrict__ cursor,
                             int2* __restrict__ entries) {
  __shared__ int sd[256];
  int b = blockIdx.x, t = threadIdx.x;
  int base = b * 1024 + t * 4;
  int v[4], loc = 0;
#pragma unroll
  for (int j = 0; j < 4; ++j) { v[j] = (base + j < N) ? cnt[base + j] + 1 : 0; loc += v[j]; }
  sd[t] = loc; __syncthreads();
  for (int off = 1; off < 256; off <<= 1) {
    int x = (t >= off) ? sd[t - off] : 0;
    __syncthreads();
    sd[t] += x;
    __syncthreads();
  }
  int run = bsum[b] + sd[t] - loc;
#pragma unroll
  for (int j = 0; j < 4; ++j) {
    if (base + j < N) {
      int i = base + j;
      offs[i] = run;
      cursor[i] = run + 1;                               // slot 0 = self loop
      entries[run] = make_int2(i, __float_as_int(1.0f)); // raw w=1
      run += v[j];
    }
  }
  if (b == gridDim.x - 1 && t == 255) offs[N] = run;  // total = N + E
}

// CSR fill only (4 edges/thread, 4 independent atomic chains)
__global__ __launch_bounds__(256) void k_fill(
    const int* __restrict__ ei, const float* __restrict__ ew, int E,
    int* __restrict__ cursor, int2* __restrict__ entries) {
  int e0 = (blockIdx.x * 256 + threadIdx.x) * 4;
  int src[4], dst[4];
  float w[4];
#pragma unroll
  for (int j = 0; j < 4; ++j) {
    int e = e0 + j;
    if (e < E) { src[j] = ei[e]; dst[j] = ei[E + e]; w[j] = ew[e]; }
  }
  int pos[4];
#pragma unroll
  for (int j = 0; j < 4; ++j)
    if (e0 + j < E) pos[j] = atomicAdd(cursor + dst[j], 1);
#pragma unroll
  for (int j = 0; j < 4; ++j)
    if (e0 + j < E) entries[pos[j]] = make_int2(src[j], __float_as_int(w[j]));
}

// deg->dis: segmented sum of RAW weights over CSR rows (atomic-free)
__global__ void k_degdis(const int2* __restrict__ entries, const int* __restrict__ offs,
                         float* __restrict__ dis, int N) {
  int i = blockIdx.x * blockDim.x + threadIdx.x;
  if (i >= N) return;
  int p = offs[i], pe = offs[i + 1];
  float d = 0.f;
  for (; p < pe; ++p) d += __int_as_float(entries[p].y);
  dis[i] = d > 0.f ? rsqrtf(fmaxf(d, 1e-12f)) : 0.f;
}

// fold dis[src] into entries.y (sequential r/m/w, coalesced)
__global__ void k_prenorm(int2* __restrict__ entries, const float* __restrict__ dis, int NE) {
  int p = blockIdx.x * blockDim.x + threadIdx.x;
  if (p >= NE) return;
  int2 e = entries[p];
  entries[p].y = __float_as_int(__int_as_float(e.y) * dis[e.x]);
}

// half-wave gather-accumulate: 32 lanes, each lane covers 2 cols (ushort2).
__device__ __forceinline__ void row_gather2(const unsigned short* __restrict__ xin,
                                            const int2* __restrict__ entries,
                                            int p, int pe, int l32,
                                            float& ra0, float& ra1) {
  float a0 = 0.f, a1 = 0.f;
  for (; p + 8 <= pe; p += 8) {
    int2 e[8];
#pragma unroll
    for (int j = 0; j < 8; ++j) e[j] = entries[p + j];
    unsigned x[8];
#pragma unroll
    for (int j = 0; j < 8; ++j)
      x[j] = *(const unsigned*)(xin + ((size_t)e[j].x << 6) + (l32 << 1));
#pragma unroll
    for (int j = 0; j < 8; ++j) {
      float w = __int_as_float(e[j].y);
      a0 = fmaf(bf2f((unsigned short)(x[j] & 0xffffu)), w, a0);
      a1 = fmaf(bf2f((unsigned short)(x[j] >> 16)), w, a1);
    }
  }
  if (p + 4 <= pe) {
    int2 e[4];
#pragma unroll
    for (int j = 0; j < 4; ++j) e[j] = entries[p + j];
    unsigned x[4];
#pragma unroll
    for (int j = 0; j < 4; ++j)
      x[j] = *(const unsigned*)(xin + ((size_t)e[j].x << 6) + (l32 << 1));
#pragma unroll
    for (int j = 0; j < 4; ++j) {
      float w = __int_as_float(e[j].y);
      a0 = fmaf(bf2f((unsigned short)(x[j] & 0xffffu)), w, a0);
      a1 = fmaf(bf2f((unsigned short)(x[j] >> 16)), w, a1);
    }
    p += 4;
  }
  if (p + 2 <= pe) {
    int2 e0 = entries[p], e1 = entries[p + 1];
    unsigned x0 = *(const unsigned*)(xin + ((size_t)e0.x << 6) + (l32 << 1));
    unsigned x1 = *(const unsigned*)(xin + ((size_t)e1.x << 6) + (l32 << 1));
    float w0 = __int_as_float(e0.y), w1 = __int_as_float(e1.y);
    a0 = fmaf(bf2f((unsigned short)(x0 & 0xffffu)), w0, a0);
    a1 = fmaf(bf2f((unsigned short)(x0 >> 16)), w0, a1);
    a0 = fmaf(bf2f((unsigned short)(x1 & 0xffffu)), w1, a0);
    a1 = fmaf(bf2f((unsigned short)(x1 >> 16)), w1, a1);
    p += 2;
  }
  if (p < pe) {
    int2 e = entries[p];
    unsigned x = *(const unsigned*)(xin + ((size_t)e.x << 6) + (l32 << 1));
    float w = __int_as_float(e.y);
    a0 = fmaf(bf2f((unsigned short)(x & 0xffffu)), w, a0);
    a1 = fmaf(bf2f((unsigned short)(x >> 16)), w, a1);
  }
  ra0 = a0; ra1 = a1;
}

// layer-1 aggregation: half-wave per node, ushort2 out (permuted pos layout)
__global__ void k_agg(const unsigned short* __restrict__ xin, const int2* __restrict__ entries,
                      const int* __restrict__ offs, const float* __restrict__ dis,
                      const float* __restrict__ bias, unsigned short* __restrict__ xout, int N) {
  const int tid = threadIdx.x;
  const int l32 = tid & 31;
  int i = blockIdx.x * 8 + (tid >> 5);
  if (i >= N) return;
  float a0, a1;
  row_gather2(xin, entries, offs[i], offs[i + 1], l32, a0, a1);
  float d = dis[i];
  a0 = fmaf(a0, d, bias[permcol(2 * l32)]);
  a1 = fmaf(a1, d, bias[permcol(2 * l32 + 1)]);
  a0 = fmaxf(a0, 0.f);
  a1 = fmaxf(a1, 0.f);
  ushort2 pk;
  pk.x = f2bf(a0);
  pk.y = f2bf(a1);
  *(ushort2*)(xout + ((size_t)i << 6) + (l32 << 1)) = pk;
}

// masked layer-2 aggregation: half-wave per masked node, fp32 out + y[mask]
__global__ void k_agg2m(const unsigned short* __restrict__ xin, const int2* __restrict__ entries,
                        const int* __restrict__ offs, const float* __restrict__ dis,
                        const int* __restrict__ mask, const int* __restrict__ y,
                        float* __restrict__ tout, float* __restrict__ outY, int M) {
  const int tid = threadIdx.x;
  const int l32 = tid & 31;
  int o = blockIdx.x * 8 + (tid >> 5);
  if (o >= M) return;
  int i = mask[o];
  float a0, a1;
  row_gather2(xin, entries, offs[i], offs[i + 1], l32, a0, a1);
  float d = dis[i];
  float2 pk;
  pk.x = a0 * d;
  pk.y = a1 * d;
  *(float2*)(tout + ((size_t)o << 6) + (l32 << 1)) = pk;
  if (l32 == 0) outY[o] = (float)y[i];
}

// final projection [M,64]@[64,64]+b2 via MFMA (permuted-k packed W2), fp32 out
__global__ __launch_bounds__(256) void k_mfma_final(
    const float* __restrict__ X, const unsigned short* __restrict__ packW2,
    const float* __restrict__ b2, float* __restrict__ out, int M) {
  mfma_gemm_body<false, true, false, 2>(X, 64, nullptr, packW2, nullptr, 2, 64,
                                        b2, out, M, blockIdx.x * 4 + (threadIdx.x >> 6));
}

extern "C" void kernel_launch(void* const* d_in, const int* in_sizes, int n_in,
                              void* d_out, int out_size, void* d_ws, size_t ws_size,
                              hipStream_t stream) {
  const float* doc   = (const float*)d_in[0];
  const float* wordf = (const float*)d_in[1];
  const float* ew    = (const float*)d_in[2];
  const float* Wlin  = (const float*)d_in[3];
  const float* blin  = (const float*)d_in[4];
  const float* W1    = (const float*)d_in[5];
  const float* b1    = (const float*)d_in[6];
  const float* W2    = (const float*)d_in[7];
  const float* b2    = (const float*)d_in[8];
  const int*   ei    = (const int*)d_in[9];
  const int*   mask  = (const int*)d_in[10];
  const int*   y     = (const int*)d_in[11];

  const int E  = in_sizes[2];
  const int M  = in_sizes[10];
  const int ND = in_sizes[0] / 768;
  const int NW = in_sizes[1] / 300;
  const int N  = ND + NW;
  const int NE = N + E;

  // workspace carve (aligned 256B)
  char* p = (char*)d_ws;
  auto carve = [&](size_t bytes) -> void* {
    void* q = (void*)p;
    p += (bytes + 255) & ~(size_t)255;
    return q;
  };
  float*          WfuseB = (float*)carve(301 * 64 * 4);
  unsigned short* packW1 = (unsigned short*)carve((size_t)4 * 24 * 64 * 8 * 2);
  unsigned short* packW2 = (unsigned short*)carve((size_t)4 * 2 * 64 * 8 * 2);
  float* dis    = (float*)carve((size_t)N * 4);
  int*   cnt    = (int*)carve((size_t)N * 4);
  int*   offs   = (int*)carve(((size_t)N + 1) * 4);
  int*   cursor = (int*)carve((size_t)N * 4);
  int*   bsum   = (int*)carve(1024);
  int2*  entries = (int2*)carve((size_t)NE * 8);
  unsigned short* xw1 = (unsigned short*)carve((size_t)N * 64 * 2);  // bf16, permuted cols
  unsigned short* h1  = (unsigned short*)carve((size_t)N * 64 * 2);  // bf16, permuted cols
  float* tmask = (float*)carve((size_t)M * 64 * 4);                  // fp32, permuted cols

  hipMemsetAsync(cnt, 0, (size_t)N * 4, stream);

  // k_pre: fuse MFMA (strided B) || pack W1 || pack W2
  const int fuseBlocks = (301 + 127) / 128;   // RS=2: 32 rows/wave, 4 waves/blk
  k_pre<<<fuseBlocks + 24 + 2, 256, 0, stream>>>(
      Wlin, blin, W1, WfuseB, packW1, W2, packW2, fuseBlocks);

  // k_main: doc MFMA || word MFMA (strided WfuseB) || cnt histogram
  const int docBlocks  = (ND + 127) / 128;
  const int wordBlocks = (NW + 127) / 128;
  const int cntBlocks  = (E + 1023) / 1024;
  k_main<<<docBlocks + wordBlocks + cntBlocks, 256, 0, stream>>>(
      doc, packW1, xw1, ND, docBlocks,
      wordf, WfuseB, WfuseB + (size_t)300 * 64, xw1 + (size_t)ND * 64, NW, wordBlocks,
      ei, E, cnt);

  int nb = (N + 1023) / 1024;
  k_scan_reduce<<<nb, 256, 0, stream>>>(cnt, N, bsum);
  k_scan_small<<<1, 128, 0, stream>>>(bsum, nb);
  k_scan_final<<<nb, 256, 0, stream>>>(cnt, N, bsum, offs, cursor, entries);

  // CSR fill
  k_fill<<<(E + 1023) / 1024, 256, 0, stream>>>(ei, ew, E, cursor, entries);

  k_degdis<<<(N + 255) / 256, 256, 0, stream>>>(entries, offs, dis, N);
  k_prenorm<<<(NE + 255) / 256, 256, 0, stream>>>(entries, dis, NE);

  // layer-1 aggregation (+b1 via pi, relu) -> bf16 h1 (permuted)
  k_agg<<<(N + 7) / 8, 256, 0, stream>>>(xw1, entries, offs, dis, b1, h1, N);

  // layer-2: masked aggregation over h1, then project [M,64]@[64,64]+b2
  float* out0 = (float*)d_out;
  float* outY = out0 + (size_t)M * 64;
  k_agg2m<<<(M + 7) / 8, 256, 0, stream>>>(h1, entries, offs, dis, mask, y, tmask, outY, M);
  k_mfma_final<<<(M + 127) / 128, 256, 0, stream>>>(tmask, packW2, b2, out0, M);
}